// Round 12
// baseline (142.017 us; speedup 1.0000x reference)
//
#include <hip/hip_runtime.h>
#include <stdint.h>

#define N_ 256
#define H_ 1024
#define BS_ 128

// ---------------- workspace layout (floats), all plain stores ----------------
// sk   : [128][1024]        @ 0          1 - tk^2
// oacc : [3][128][256]      @ 131072     reduced fo/go/ko
// opart: [32][3][128][256]  @ 229376     layer2 k-split partials (32-wide slices)
// jpart: [32][2][128][256]  @ 3375104    J h-split partials
#define WS_SK    0
#define WS_OACC  131072
#define WS_OPART 229376
#define WS_JPART 3375104
#define WS_FLOATS 5472256   // ~21.9 MB

// ---- K12: fused layer1+layer2-partial. grid = 96 groups x 8 row-tiles = 768 ----
// 32-wide h/k-slices: same 48 MB weight traffic as R10 (set by 16 rows/block)
// but 2x the blocks -> 3 blocks/CU. XCD swizzle: bx = g + 96*rt (96%8==0).
__global__ __launch_bounds__(256) void k12_l1l2(
    const float* __restrict__ x,
    const float* __restrict__ Wf1, const float* __restrict__ bf1,
    const float* __restrict__ Wg1, const float* __restrict__ bg1,
    const float* __restrict__ Wk1, const float* __restrict__ bk1,
    const float* __restrict__ Wf2, const float* __restrict__ bf2,
    const float* __restrict__ Wg2, const float* __restrict__ bg2,
    const float* __restrict__ Wk2, const float* __restrict__ bk2,
    float* __restrict__ sk, float* __restrict__ opart)
{
    const int bx = blockIdx.x;
    const int g  = bx % 96;            // weight-sharing group
    const int rt = bx / 96;            // 0..7 row tile (16 rows)
    const int m  = g >> 5;             // 0..2
    const int ht = g & 31;             // 0..31  (32-wide h-slice = k-slice)
    const int t  = threadIdx.x;
    const int h0 = ht * 32;
    const int r0 = rt * 16;

    const float* W1 = (m == 0) ? Wf1 : (m == 1) ? Wg1 : Wk1;
    const float* b1 = (m == 0) ? bf1 : (m == 1) ? bg1 : bk1;
    const float* W2 = (m == 0) ? Wf2 : (m == 1) ? Wg2 : Wk2;
    const float* b2 = (m == 0) ? bf2 : (m == 1) ? bg2 : bk2;

    __shared__ float xs[16][256];      // 16 KB
    __shared__ float ts[16][32];       // 2 KB
    for (int u = t; u < 4096; u += 256)
        xs[u >> 8][u & 255] = x[(r0 + (u >> 8)) * N_ + (u & 255)];
    __syncthreads();

    // ---- phase 1: thread = (hl = t&31, row-pair rg = (t>>5)*2) ----
    {
        const int hl = t & 31;
        const int rg = (t >> 5) * 2;
        const int h  = h0 + hl;
        float a0 = b1[h], a1 = a0;
        const float4* w4 = (const float4*)(W1 + h * N_);
        const float4* x0 = (const float4*)xs[rg];
        const float4* x1 = (const float4*)xs[rg + 1];
        #pragma unroll 8
        for (int c = 0; c < 64; ++c) {
            float4 w = w4[c];
            float4 p = x0[c];                    // 2-addr/wave LDS: free
            a0 += w.x * p.x + w.y * p.y + w.z * p.z + w.w * p.w;
            float4 q = x1[c];
            a1 += w.x * q.x + w.y * q.y + w.z * q.z + w.w * q.w;
        }
        const float v0 = tanhf(a0), v1 = tanhf(a1);
        ts[rg][hl]     = v0;
        ts[rg + 1][hl] = v1;
        if (m == 2) {
            sk[(r0 + rg) * H_ + h]     = 1.0f - v0 * v0;
            sk[(r0 + rg + 1) * H_ + h] = 1.0f - v1 * v1;
        }
    }
    __syncthreads();

    // ---- phase 2: thread = output channel i; 16-row partial over 32-k slice --
    {
        float acc[16];
        const float bv = (ht == 0) ? b2[t] : 0.0f;
        #pragma unroll
        for (int r = 0; r < 16; ++r) acc[r] = bv;

        const float4* w4 = (const float4*)(W2 + t * H_ + h0);
        #pragma unroll 2
        for (int c = 0; c < 8; ++c) {
            float4 w = w4[c];
            #pragma unroll
            for (int r = 0; r < 16; ++r) {
                float4 a = ((const float4*)ts[r])[c];   // wave-uniform broadcast
                acc[r] += w.x * a.x + w.y * a.y + w.z * a.z + w.w * a.w;
            }
        }
        #pragma unroll
        for (int r = 0; r < 16; ++r)
            opart[((ht * 3 + m) * BS_ + r0 + r) * N_ + t] = acc[r];
    }
}

// ---- K25: reduce opart -> oacc once. grid = 384 blocks ----
__global__ __launch_bounds__(256) void k25_reduce(
    const float* __restrict__ opart, float* __restrict__ oacc)
{
    const int tid = blockIdx.x * 256 + threadIdx.x;   // 0..98303
    float s = 0.f;
    #pragma unroll
    for (int ks = 0; ks < 32; ++ks)
        s += opart[ks * (3 * BS_ * N_) + tid];
    oacc[tid] = s;
}

// ---- K3: fused v+J partials. grid = 16rp(8rows) x 32q(32h) = 512 ----
// 8 rows/block halves Wk1/Wk2 re-reads (64 -> 32 MB) at unchanged 2 blocks/CU.
// XCD swizzle: bx = q + 32*rp (32%8==0).
__global__ __launch_bounds__(256) void k3_vj(
    const float* __restrict__ Wk1, const float* __restrict__ Wk2,
    const float* __restrict__ oacc, const float* __restrict__ sk,
    float* __restrict__ jpart)
{
    const int q  = blockIdx.x & 31;    // 0..31 h-slice (32 wide)
    const int rp = blockIdx.x >> 5;    // 0..15 row tile (8 rows)
    const int t  = threadIdx.x;
    const int r0 = rp * 8;
    const int h0 = q * 32;

    __shared__ float fos[8][256], gos[8][256];   // 16 KB
    __shared__ float sfv[8][32], sgv[8][32];     // 2 KB

    for (int u = t; u < 2048; u += 256) {
        const int r = u >> 8, i = u & 255;
        fos[r][i] = oacc[(r0 + r) * N_ + i];
        gos[r][i] = oacc[(BS_ + r0 + r) * N_ + i];
    }
    __syncthreads();

    // ---- phase A: v[r][h] = sum_i o[r][i]*Wk2[i][h]; thread = (hl, rl=t>>5) --
    {
        const int hl = t & 31;
        const int rl = t >> 5;         // 0..7 (2 addrs/wave: free broadcast)
        const int h  = h0 + hl;
        const float* w2 = Wk2 + h;
        float vf = 0.f, vg = 0.f;
        #pragma unroll 8
        for (int c = 0; c < 64; ++c) {
            const float4 of = ((const float4*)fos[rl])[c];
            const float4 og = ((const float4*)gos[rl])[c];
            const float w0 = w2[(4 * c + 0) * H_];
            const float w1 = w2[(4 * c + 1) * H_];
            const float w2v = w2[(4 * c + 2) * H_];
            const float w3 = w2[(4 * c + 3) * H_];
            vf += of.x * w0 + of.y * w1 + of.z * w2v + of.w * w3;
            vg += og.x * w0 + og.y * w1 + og.z * w2v + og.w * w3;
        }
        const float s = sk[(r0 + rl) * H_ + h];
        sfv[rl][hl] = s * vf;
        sgv[rl][hl] = s * vg;
    }
    __syncthreads();

    // ---- phase B: J[r][j] = sum_hh sfv[r][hh]*Wk1[h0+hh][j]; thread = j ----
    {
        float jf[8] = {0.f, 0.f, 0.f, 0.f, 0.f, 0.f, 0.f, 0.f};
        float jg[8] = {0.f, 0.f, 0.f, 0.f, 0.f, 0.f, 0.f, 0.f};
        const float* w1 = Wk1 + h0 * N_ + t;    // coalesced over t
        #pragma unroll 2
        for (int c = 0; c < 8; ++c) {
            const float w0 = w1[(4 * c + 0) * N_];
            const float wv1 = w1[(4 * c + 1) * N_];
            const float wv2 = w1[(4 * c + 2) * N_];
            const float wv3 = w1[(4 * c + 3) * N_];
            #pragma unroll
            for (int r = 0; r < 8; ++r) {
                const float4 sf = ((const float4*)sfv[r])[c];   // broadcast b128
                const float4 sg = ((const float4*)sgv[r])[c];
                jf[r] += sf.x * w0 + sf.y * wv1 + sf.z * wv2 + sf.w * wv3;
                jg[r] += sg.x * w0 + sg.y * wv1 + sg.z * wv2 + sg.w * wv3;
            }
        }
        #pragma unroll
        for (int r = 0; r < 8; ++r) {
            jpart[((q * 2 + 0) * BS_ + r0 + r) * N_ + t] = jf[r];
            jpart[((q * 2 + 1) * BS_ + r0 + r) * N_ + t] = jg[r];
        }
    }
}

// ---- K4: reduce jpart + norms + mask + output. grid = 128 ----
__global__ __launch_bounds__(256) void k4_final(
    const float* __restrict__ oacc,
    const float* __restrict__ jpart,
    float* __restrict__ out)
{
    const int r = blockIdx.x;
    const int t = threadIdx.x;
    __shared__ float red[12];

    const float fo = oacc[r * N_ + t];
    const float go = oacc[(BS_ + r) * N_ + t];
    const float ko = oacc[(2 * BS_ + r) * N_ + t];

    float jf = 0.f, jg = 0.f;
    #pragma unroll
    for (int q = 0; q < 32; ++q) {
        jf += jpart[((q * 2 + 0) * BS_ + r) * N_ + t];
        jg += jpart[((q * 2 + 1) * BS_ + r) * N_ + t];
    }

    float v0 = ko * ko, v1 = jf * jf, v2 = ko * jg;
    #pragma unroll
    for (int o = 32; o > 0; o >>= 1) {
        v0 += __shfl_xor(v0, o, 64);
        v1 += __shfl_xor(v1, o, 64);
        v2 += __shfl_xor(v2, o, 64);
    }
    const int wid = t >> 6;
    if ((t & 63) == 0) {
        red[wid * 3 + 0] = v0;
        red[wid * 3 + 1] = v1;
        red[wid * 3 + 2] = v2;
    }
    __syncthreads();
    const float kn2 = red[0] + red[3] + red[6] + red[9];
    const float jf2 = red[1] + red[4] + red[7] + red[10];
    const float kjg = red[2] + red[5] + red[8] + red[11];

    const float knorm = sqrtf(kn2);
    const float kn4 = kn2 * kn2;
    const float kn8 = kn4 * kn4;
    const float c1 = sqrtf(jf2) - 60.0f * kn8 * knorm;
    const float c2 = kjg - 20.0f * kn8 * kn2;
    const float scale = ((c1 > 1e-8f) || (c2 < -1e-8f)) ? 0.5f : 1.0f;

    out[r * N_ + t] = (fo + go) * scale;
}

// ================= fallback: round-2 proven fused kernel =================
__global__ __launch_bounds__(256) void manifold_fused(
    const float* __restrict__ x,
    const float* __restrict__ Wf1, const float* __restrict__ bf1v,
    const float* __restrict__ Wf2, const float* __restrict__ bf2v,
    const float* __restrict__ Wg1, const float* __restrict__ bg1v,
    const float* __restrict__ Wg2, const float* __restrict__ bg2v,
    const float* __restrict__ Wk1, const float* __restrict__ bk1v,
    const float* __restrict__ Wk2, const float* __restrict__ bk2v,
    float* __restrict__ out)
{
    const int b = blockIdx.x;
    const int t = threadIdx.x;
    __shared__ float xs[N_];
    __shared__ float tf[H_], tg[H_], tk[H_], sk[H_];
    __shared__ float fo[N_], go[N_];
    __shared__ float sfv[H_], sgv[H_];
    __shared__ float red[12];

    xs[t] = x[b * N_ + t];
    __syncthreads();
    {
        float acc[12];
        const float4* rows[12];
        #pragma unroll
        for (int m = 0; m < 4; ++m) {
            const int h = t + m * 256;
            rows[m]     = (const float4*)(Wf1 + h * N_);
            rows[4 + m] = (const float4*)(Wg1 + h * N_);
            rows[8 + m] = (const float4*)(Wk1 + h * N_);
            acc[m] = bf1v[h]; acc[4 + m] = bg1v[h]; acc[8 + m] = bk1v[h];
        }
        const float4* xs4 = (const float4*)xs;
        #pragma unroll 2
        for (int c = 0; c < 64; ++c) {
            float4 a = xs4[c];
            #pragma unroll
            for (int r = 0; r < 12; ++r) {
                float4 w = rows[r][c];
                acc[r] += w.x * a.x + w.y * a.y + w.z * a.z + w.w * a.w;
            }
        }
        #pragma unroll
        for (int m = 0; m < 4; ++m) {
            const int h = t + m * 256;
            float vtf = tanhf(acc[m]);
            float vtg = tanhf(acc[4 + m]);
            float vtk = tanhf(acc[8 + m]);
            tf[h] = vtf; tg[h] = vtg; tk[h] = vtk; sk[h] = 1.0f - vtk * vtk;
        }
    }
    __syncthreads();
    float af = bf2v[t], ag = bg2v[t], ak = bk2v[t];
    {
        const float4* rf = (const float4*)(Wf2 + t * H_);
        const float4* rg = (const float4*)(Wg2 + t * H_);
        const float4* rk = (const float4*)(Wk2 + t * H_);
        #pragma unroll 2
        for (int c = 0; c < 256; ++c) {
            float4 wf = rf[c], wg = rg[c], wk = rk[c];
            float4 vf = ((const float4*)tf)[c];
            af += wf.x*vf.x + wf.y*vf.y + wf.z*vf.z + wf.w*vf.w;
            float4 vg = ((const float4*)tg)[c];
            ag += wg.x*vg.x + wg.y*vg.y + wg.z*vg.z + wg.w*vg.w;
            float4 vk = ((const float4*)tk)[c];
            ak += wk.x*vk.x + wk.y*vk.y + wk.z*vk.z + wk.w*vk.w;
        }
    }
    fo[t] = af; go[t] = ag;
    __syncthreads();
    {
        float vf[4] = {0.f,0.f,0.f,0.f}, vg[4] = {0.f,0.f,0.f,0.f};
        const float* base = Wk2 + 4 * t;
        #pragma unroll 4
        for (int i = 0; i < N_; ++i) {
            float4 w = *(const float4*)(base + i * H_);
            float fv = fo[i], gv = go[i];
            vf[0]+=w.x*fv; vf[1]+=w.y*fv; vf[2]+=w.z*fv; vf[3]+=w.w*fv;
            vg[0]+=w.x*gv; vg[1]+=w.y*gv; vg[2]+=w.z*gv; vg[3]+=w.w*gv;
        }
        #pragma unroll
        for (int c = 0; c < 4; ++c) {
            sfv[4*t+c] = sk[4*t+c]*vf[c];
            sgv[4*t+c] = sk[4*t+c]*vg[c];
        }
    }
    __syncthreads();
    float jf = 0.f, jg = 0.f;
    {
        const float* col = Wk1 + t;
        #pragma unroll 4
        for (int c = 0; c < 256; ++c) {
            float4 s4 = ((const float4*)sfv)[c];
            float4 g4 = ((const float4*)sgv)[c];
            const int h = c * 4;
            float w0 = col[(h+0)*N_], w1 = col[(h+1)*N_];
            float w2 = col[(h+2)*N_], w3 = col[(h+3)*N_];
            jf += s4.x*w0 + s4.y*w1 + s4.z*w2 + s4.w*w3;
            jg += g4.x*w0 + g4.y*w1 + g4.z*w2 + g4.w*w3;
        }
    }
    float v0 = ak*ak, v1 = jf*jf, v2 = ak*jg;
    #pragma unroll
    for (int o = 32; o > 0; o >>= 1) {
        v0 += __shfl_xor(v0, o, 64);
        v1 += __shfl_xor(v1, o, 64);
        v2 += __shfl_xor(v2, o, 64);
    }
    const int wid = t >> 6;
    if ((t & 63) == 0) {
        red[wid*3+0] = v0; red[wid*3+1] = v1; red[wid*3+2] = v2;
    }
    __syncthreads();
    const float kn2 = red[0]+red[3]+red[6]+red[9];
    const float jf2 = red[1]+red[4]+red[7]+red[10];
    const float kjg = red[2]+red[5]+red[8]+red[11];
    const float knorm = sqrtf(kn2);
    const float kn4 = kn2*kn2, kn8 = kn4*kn4;
    const float c1 = sqrtf(jf2) - 60.0f*kn8*knorm;
    const float c2 = kjg - 20.0f*kn8*kn2;
    const float scale = ((c1 > 1e-8f) || (c2 < -1e-8f)) ? 0.5f : 1.0f;
    out[b*N_+t] = (af+ag)*scale;
}

extern "C" void kernel_launch(void* const* d_in, const int* in_sizes, int n_in,
                              void* d_out, int out_size, void* d_ws, size_t ws_size,
                              hipStream_t stream) {
    const float* x    = (const float*)d_in[1];
    const float* Wf1  = (const float*)d_in[2];
    const float* bf1v = (const float*)d_in[3];
    const float* Wf2  = (const float*)d_in[4];
    const float* bf2v = (const float*)d_in[5];
    const float* Wg1  = (const float*)d_in[6];
    const float* bg1v = (const float*)d_in[7];
    const float* Wg2  = (const float*)d_in[8];
    const float* bg2v = (const float*)d_in[9];
    const float* Wk1  = (const float*)d_in[10];
    const float* bk1v = (const float*)d_in[11];
    const float* Wk2  = (const float*)d_in[12];
    const float* bk2v = (const float*)d_in[13];
    float* out = (float*)d_out;

    if (ws_size < (size_t)WS_FLOATS * sizeof(float)) {
        manifold_fused<<<BS_, 256, 0, stream>>>(
            x, Wf1, bf1v, Wf2, bf2v, Wg1, bg1v, Wg2, bg2v,
            Wk1, bk1v, Wk2, bk2v, out);
        return;
    }

    float* ws    = (float*)d_ws;
    float* sk    = ws + WS_SK;
    float* oacc  = ws + WS_OACC;
    float* opart = ws + WS_OPART;
    float* jpart = ws + WS_JPART;

    k12_l1l2  <<<768, 256, 0, stream>>>(x, Wf1, bf1v, Wg1, bg1v, Wk1, bk1v,
                                        Wf2, bf2v, Wg2, bg2v, Wk2, bk2v,
                                        sk, opart);
    k25_reduce<<<384, 256, 0, stream>>>(opart, oacc);
    k3_vj     <<<512, 256, 0, stream>>>(Wk1, Wk2, oacc, sk, jpart);
    k4_final  <<<BS_, 256, 0, stream>>>(oacc, jpart, out);
}

// Round 13
// 136.379 us; speedup vs baseline: 1.0413x; 1.0413x over previous
//
#include <hip/hip_runtime.h>
#include <stdint.h>

#define N_ 256
#define H_ 1024
#define BS_ 128

// ---------------- workspace layout (floats), all plain stores ----------------
// sk   : [128][1024]        @ 0          1 - tk^2
// oacc : [3][128][256]      @ 131072     reduced fo/go/ko
// opart: [16][3][128][256]  @ 229376     layer2 k-split partials
// jpart: [16][2][128][256]  @ 1802240    J h-split partials
#define WS_SK    0
#define WS_OACC  131072
#define WS_OPART 229376
#define WS_JPART 1802240
#define WS_FLOATS 2850816   // ~11.4 MB

// ---- K12: fused layer1+layer2-partial. grid = 48 groups x 8 row-tiles = 384 ----
// 64-wide slices (full wave coalescing), 16 rows/block -> 48 MB weight traffic.
// XCD swizzle: bx = g + 48*rt -> bx%8 == g%8.
__global__ __launch_bounds__(256) void k12_l1l2(
    const float* __restrict__ x,
    const float* __restrict__ Wf1, const float* __restrict__ bf1,
    const float* __restrict__ Wg1, const float* __restrict__ bg1,
    const float* __restrict__ Wk1, const float* __restrict__ bk1,
    const float* __restrict__ Wf2, const float* __restrict__ bf2,
    const float* __restrict__ Wg2, const float* __restrict__ bg2,
    const float* __restrict__ Wk2, const float* __restrict__ bk2,
    float* __restrict__ sk, float* __restrict__ opart)
{
    const int bx = blockIdx.x;
    const int g  = bx % 48;            // weight-sharing group
    const int rt = bx / 48;            // 0..7 row tile (16 rows)
    const int m  = g >> 4;             // 0..2
    const int ht = g & 15;             // 0..15  (64-wide h-slice = k-slice)
    const int t  = threadIdx.x;
    const int h0 = ht * 64;
    const int r0 = rt * 16;

    const float* W1 = (m == 0) ? Wf1 : (m == 1) ? Wg1 : Wk1;
    const float* b1 = (m == 0) ? bf1 : (m == 1) ? bg1 : bk1;
    const float* W2 = (m == 0) ? Wf2 : (m == 1) ? Wg2 : Wk2;
    const float* b2 = (m == 0) ? bf2 : (m == 1) ? bg2 : bk2;

    __shared__ float xs[16][256];      // 16 KB
    __shared__ float ts[16][64];       // 4 KB
    for (int u = t; u < 4096; u += 256)
        xs[u >> 8][u & 255] = x[(r0 + (u >> 8)) * N_ + (u & 255)];
    __syncthreads();

    // ---- phase 1: thread = (hl = t&63, row-quad rq = (t>>6)*4) ----
    {
        const int hl = t & 63;
        const int rq = (t >> 6) * 4;
        const int h  = h0 + hl;
        float a0 = b1[h], a1 = a0, a2 = a0, a3 = a0;
        const float4* w4 = (const float4*)(W1 + h * N_);
        const float4* x0 = (const float4*)xs[rq];
        const float4* x1 = (const float4*)xs[rq + 1];
        const float4* x2 = (const float4*)xs[rq + 2];
        const float4* x3 = (const float4*)xs[rq + 3];
        #pragma unroll 8
        for (int c = 0; c < 64; ++c) {
            float4 w = w4[c];
            float4 p = x0[c];                    // broadcast LDS reads
            a0 += w.x * p.x + w.y * p.y + w.z * p.z + w.w * p.w;
            float4 q = x1[c];
            a1 += w.x * q.x + w.y * q.y + w.z * q.z + w.w * q.w;
            float4 r = x2[c];
            a2 += w.x * r.x + w.y * r.y + w.z * r.z + w.w * r.w;
            float4 s = x3[c];
            a3 += w.x * s.x + w.y * s.y + w.z * s.z + w.w * s.w;
        }
        const float v0 = tanhf(a0), v1 = tanhf(a1);
        const float v2 = tanhf(a2), v3 = tanhf(a3);
        ts[rq][hl] = v0; ts[rq + 1][hl] = v1;
        ts[rq + 2][hl] = v2; ts[rq + 3][hl] = v3;
        if (m == 2) {
            sk[(r0 + rq) * H_ + h]     = 1.0f - v0 * v0;
            sk[(r0 + rq + 1) * H_ + h] = 1.0f - v1 * v1;
            sk[(r0 + rq + 2) * H_ + h] = 1.0f - v2 * v2;
            sk[(r0 + rq + 3) * H_ + h] = 1.0f - v3 * v3;
        }
    }
    __syncthreads();

    // ---- phase 2: thread = output channel i; 16-row partial over the slice --
    {
        float acc[16];
        const float bv = (ht == 0) ? b2[t] : 0.0f;
        #pragma unroll
        for (int r = 0; r < 16; ++r) acc[r] = bv;

        const float4* w4 = (const float4*)(W2 + t * H_ + h0);
        #pragma unroll 2
        for (int c = 0; c < 16; ++c) {
            float4 w = w4[c];
            #pragma unroll
            for (int r = 0; r < 16; ++r) {
                float4 a = ((const float4*)ts[r])[c];   // wave-uniform broadcast
                acc[r] += w.x * a.x + w.y * a.y + w.z * a.z + w.w * a.w;
            }
        }
        #pragma unroll
        for (int r = 0; r < 16; ++r)
            opart[((ht * 3 + m) * BS_ + r0 + r) * N_ + t] = acc[r];
    }
}

// ---- K25: reduce opart -> oacc once. grid = 384 blocks ----
__global__ __launch_bounds__(256) void k25_reduce(
    const float* __restrict__ opart, float* __restrict__ oacc)
{
    const int tid = blockIdx.x * 256 + threadIdx.x;   // 0..98303
    float s = 0.f;
    #pragma unroll
    for (int ks = 0; ks < 16; ++ks)
        s += opart[ks * (3 * BS_ * N_) + tid];
    oacc[tid] = s;
}

// ---- K3: fused v+J partials. grid = 16q(64h) x 16rp(8rows) = 256 ----
// 8 rows/block halves Wk1/Wk2 re-reads vs R11 (64 -> 32 MB), 64-wide slices
// keep full wave coalescing. XCD swizzle: bx = q + 16*rp (16%8==0).
__global__ __launch_bounds__(256) void k3_vj(
    const float* __restrict__ Wk1, const float* __restrict__ Wk2,
    const float* __restrict__ oacc, const float* __restrict__ sk,
    float* __restrict__ jpart)
{
    const int q  = blockIdx.x & 15;    // 0..15 h-slice (64 wide)
    const int rp = blockIdx.x >> 4;    // 0..15 row tile (8 rows)
    const int t  = threadIdx.x;
    const int r0 = rp * 8;
    const int h0 = q * 64;

    __shared__ float fos[8][256], gos[8][256];   // 16 KB
    __shared__ float sfv[8][64], sgv[8][64];     // 4 KB

    for (int u = t; u < 2048; u += 256) {
        const int r = u >> 8, i = u & 255;
        fos[r][i] = oacc[(r0 + r) * N_ + i];
        gos[r][i] = oacc[(BS_ + r0 + r) * N_ + i];
    }
    __syncthreads();

    // ---- phase A: v[r][h] = sum_i o[r][i]*Wk2[i][h] ----
    // thread = (hl = t&63, wave w = t>>6) owns rows w and w+4 (2x ILP)
    {
        const int hl = t & 63;
        const int w  = t >> 6;         // 0..3, wave-uniform
        const int h  = h0 + hl;
        const float* w2 = Wk2 + h;
        float vf0 = 0.f, vg0 = 0.f, vf1 = 0.f, vg1 = 0.f;
        #pragma unroll 8
        for (int c = 0; c < 64; ++c) {
            const float4 oa = ((const float4*)fos[w])[c];       // broadcast b128
            const float4 ob = ((const float4*)fos[w + 4])[c];
            const float4 ga = ((const float4*)gos[w])[c];
            const float4 gb = ((const float4*)gos[w + 4])[c];
            const float w0 = w2[(4 * c + 0) * H_];
            const float w1 = w2[(4 * c + 1) * H_];
            const float w2v = w2[(4 * c + 2) * H_];
            const float w3 = w2[(4 * c + 3) * H_];
            vf0 += oa.x * w0 + oa.y * w1 + oa.z * w2v + oa.w * w3;
            vf1 += ob.x * w0 + ob.y * w1 + ob.z * w2v + ob.w * w3;
            vg0 += ga.x * w0 + ga.y * w1 + ga.z * w2v + ga.w * w3;
            vg1 += gb.x * w0 + gb.y * w1 + gb.z * w2v + gb.w * w3;
        }
        const float s0 = sk[(r0 + w) * H_ + h];
        const float s1 = sk[(r0 + w + 4) * H_ + h];
        sfv[w][hl]     = s0 * vf0;
        sfv[w + 4][hl] = s1 * vf1;
        sgv[w][hl]     = s0 * vg0;
        sgv[w + 4][hl] = s1 * vg1;
    }
    __syncthreads();

    // ---- phase B: J[r][j] = sum_hh sfv[r][hh]*Wk1[h0+hh][j]; thread = j ----
    {
        float jf[8] = {0.f, 0.f, 0.f, 0.f, 0.f, 0.f, 0.f, 0.f};
        float jg[8] = {0.f, 0.f, 0.f, 0.f, 0.f, 0.f, 0.f, 0.f};
        const float* w1 = Wk1 + h0 * N_ + t;    // coalesced over t
        #pragma unroll 2
        for (int c = 0; c < 16; ++c) {
            const float w0 = w1[(4 * c + 0) * N_];
            const float wv1 = w1[(4 * c + 1) * N_];
            const float wv2 = w1[(4 * c + 2) * N_];
            const float wv3 = w1[(4 * c + 3) * N_];
            #pragma unroll
            for (int r = 0; r < 8; ++r) {
                const float4 sf = ((const float4*)sfv[r])[c];   // broadcast b128
                const float4 sg = ((const float4*)sgv[r])[c];
                jf[r] += sf.x * w0 + sf.y * wv1 + sf.z * wv2 + sf.w * wv3;
                jg[r] += sg.x * w0 + sg.y * wv1 + sg.z * wv2 + sg.w * wv3;
            }
        }
        #pragma unroll
        for (int r = 0; r < 8; ++r) {
            jpart[((q * 2 + 0) * BS_ + r0 + r) * N_ + t] = jf[r];
            jpart[((q * 2 + 1) * BS_ + r0 + r) * N_ + t] = jg[r];
        }
    }
}

// ---- K4: reduce jpart + norms + mask + output. grid = 128 ----
__global__ __launch_bounds__(256) void k4_final(
    const float* __restrict__ oacc,
    const float* __restrict__ jpart,
    float* __restrict__ out)
{
    const int r = blockIdx.x;
    const int t = threadIdx.x;
    __shared__ float red[12];

    const float fo = oacc[r * N_ + t];
    const float go = oacc[(BS_ + r) * N_ + t];
    const float ko = oacc[(2 * BS_ + r) * N_ + t];

    float jf = 0.f, jg = 0.f;
    #pragma unroll
    for (int q = 0; q < 16; ++q) {
        jf += jpart[((q * 2 + 0) * BS_ + r) * N_ + t];
        jg += jpart[((q * 2 + 1) * BS_ + r) * N_ + t];
    }

    float v0 = ko * ko, v1 = jf * jf, v2 = ko * jg;
    #pragma unroll
    for (int o = 32; o > 0; o >>= 1) {
        v0 += __shfl_xor(v0, o, 64);
        v1 += __shfl_xor(v1, o, 64);
        v2 += __shfl_xor(v2, o, 64);
    }
    const int wid = t >> 6;
    if ((t & 63) == 0) {
        red[wid * 3 + 0] = v0;
        red[wid * 3 + 1] = v1;
        red[wid * 3 + 2] = v2;
    }
    __syncthreads();
    const float kn2 = red[0] + red[3] + red[6] + red[9];
    const float jf2 = red[1] + red[4] + red[7] + red[10];
    const float kjg = red[2] + red[5] + red[8] + red[11];

    const float knorm = sqrtf(kn2);
    const float kn4 = kn2 * kn2;
    const float kn8 = kn4 * kn4;
    const float c1 = sqrtf(jf2) - 60.0f * kn8 * knorm;
    const float c2 = kjg - 20.0f * kn8 * kn2;
    const float scale = ((c1 > 1e-8f) || (c2 < -1e-8f)) ? 0.5f : 1.0f;

    out[r * N_ + t] = (fo + go) * scale;
}

// ================= fallback: round-2 proven fused kernel =================
__global__ __launch_bounds__(256) void manifold_fused(
    const float* __restrict__ x,
    const float* __restrict__ Wf1, const float* __restrict__ bf1v,
    const float* __restrict__ Wf2, const float* __restrict__ bf2v,
    const float* __restrict__ Wg1, const float* __restrict__ bg1v,
    const float* __restrict__ Wg2, const float* __restrict__ bg2v,
    const float* __restrict__ Wk1, const float* __restrict__ bk1v,
    const float* __restrict__ Wk2, const float* __restrict__ bk2v,
    float* __restrict__ out)
{
    const int b = blockIdx.x;
    const int t = threadIdx.x;
    __shared__ float xs[N_];
    __shared__ float tf[H_], tg[H_], tk[H_], sk[H_];
    __shared__ float fo[N_], go[N_];
    __shared__ float sfv[H_], sgv[H_];
    __shared__ float red[12];

    xs[t] = x[b * N_ + t];
    __syncthreads();
    {
        float acc[12];
        const float4* rows[12];
        #pragma unroll
        for (int m = 0; m < 4; ++m) {
            const int h = t + m * 256;
            rows[m]     = (const float4*)(Wf1 + h * N_);
            rows[4 + m] = (const float4*)(Wg1 + h * N_);
            rows[8 + m] = (const float4*)(Wk1 + h * N_);
            acc[m] = bf1v[h]; acc[4 + m] = bg1v[h]; acc[8 + m] = bk1v[h];
        }
        const float4* xs4 = (const float4*)xs;
        #pragma unroll 2
        for (int c = 0; c < 64; ++c) {
            float4 a = xs4[c];
            #pragma unroll
            for (int r = 0; r < 12; ++r) {
                float4 w = rows[r][c];
                acc[r] += w.x * a.x + w.y * a.y + w.z * a.z + w.w * a.w;
            }
        }
        #pragma unroll
        for (int m = 0; m < 4; ++m) {
            const int h = t + m * 256;
            float vtf = tanhf(acc[m]);
            float vtg = tanhf(acc[4 + m]);
            float vtk = tanhf(acc[8 + m]);
            tf[h] = vtf; tg[h] = vtg; tk[h] = vtk; sk[h] = 1.0f - vtk * vtk;
        }
    }
    __syncthreads();
    float af = bf2v[t], ag = bg2v[t], ak = bk2v[t];
    {
        const float4* rf = (const float4*)(Wf2 + t * H_);
        const float4* rg = (const float4*)(Wg2 + t * H_);
        const float4* rk = (const float4*)(Wk2 + t * H_);
        #pragma unroll 2
        for (int c = 0; c < 256; ++c) {
            float4 wf = rf[c], wg = rg[c], wk = rk[c];
            float4 vf = ((const float4*)tf)[c];
            af += wf.x*vf.x + wf.y*vf.y + wf.z*vf.z + wf.w*vf.w;
            float4 vg = ((const float4*)tg)[c];
            ag += wg.x*vg.x + wg.y*vg.y + wg.z*vg.z + wg.w*vg.w;
            float4 vk = ((const float4*)tk)[c];
            ak += wk.x*vk.x + wk.y*vk.y + wk.z*vk.z + wk.w*vk.w;
        }
    }
    fo[t] = af; go[t] = ag;
    __syncthreads();
    {
        float vf[4] = {0.f,0.f,0.f,0.f}, vg[4] = {0.f,0.f,0.f,0.f};
        const float* base = Wk2 + 4 * t;
        #pragma unroll 4
        for (int i = 0; i < N_; ++i) {
            float4 w = *(const float4*)(base + i * H_);
            float fv = fo[i], gv = go[i];
            vf[0]+=w.x*fv; vf[1]+=w.y*fv; vf[2]+=w.z*fv; vf[3]+=w.w*fv;
            vg[0]+=w.x*gv; vg[1]+=w.y*gv; vg[2]+=w.z*gv; vg[3]+=w.w*gv;
        }
        #pragma unroll
        for (int c = 0; c < 4; ++c) {
            sfv[4*t+c] = sk[4*t+c]*vf[c];
            sgv[4*t+c] = sk[4*t+c]*vg[c];
        }
    }
    __syncthreads();
    float jf = 0.f, jg = 0.f;
    {
        const float* col = Wk1 + t;
        #pragma unroll 4
        for (int c = 0; c < 256; ++c) {
            float4 s4 = ((const float4*)sfv)[c];
            float4 g4 = ((const float4*)sgv)[c];
            const int h = c * 4;
            float w0 = col[(h+0)*N_], w1 = col[(h+1)*N_];
            float w2 = col[(h+2)*N_], w3 = col[(h+3)*N_];
            jf += s4.x*w0 + s4.y*w1 + s4.z*w2 + s4.w*w3;
            jg += g4.x*w0 + g4.y*w1 + g4.z*w2 + g4.w*w3;
        }
    }
    float v0 = ak*ak, v1 = jf*jf, v2 = ak*jg;
    #pragma unroll
    for (int o = 32; o > 0; o >>= 1) {
        v0 += __shfl_xor(v0, o, 64);
        v1 += __shfl_xor(v1, o, 64);
        v2 += __shfl_xor(v2, o, 64);
    }
    const int wid = t >> 6;
    if ((t & 63) == 0) {
        red[wid*3+0] = v0; red[wid*3+1] = v1; red[wid*3+2] = v2;
    }
    __syncthreads();
    const float kn2 = red[0]+red[3]+red[6]+red[9];
    const float jf2 = red[1]+red[4]+red[7]+red[10];
    const float kjg = red[2]+red[5]+red[8]+red[11];
    const float knorm = sqrtf(kn2);
    const float kn4 = kn2*kn2, kn8 = kn4*kn4;
    const float c1 = sqrtf(jf2) - 60.0f*kn8*knorm;
    const float c2 = kjg - 20.0f*kn8*kn2;
    const float scale = ((c1 > 1e-8f) || (c2 < -1e-8f)) ? 0.5f : 1.0f;
    out[b*N_+t] = (af+ag)*scale;
}

extern "C" void kernel_launch(void* const* d_in, const int* in_sizes, int n_in,
                              void* d_out, int out_size, void* d_ws, size_t ws_size,
                              hipStream_t stream) {
    const float* x    = (const float*)d_in[1];
    const float* Wf1  = (const float*)d_in[2];
    const float* bf1v = (const float*)d_in[3];
    const float* Wf2  = (const float*)d_in[4];
    const float* bf2v = (const float*)d_in[5];
    const float* Wg1  = (const float*)d_in[6];
    const float* bg1v = (const float*)d_in[7];
    const float* Wg2  = (const float*)d_in[8];
    const float* bg2v = (const float*)d_in[9];
    const float* Wk1  = (const float*)d_in[10];
    const float* bk1v = (const float*)d_in[11];
    const float* Wk2  = (const float*)d_in[12];
    const float* bk2v = (const float*)d_in[13];
    float* out = (float*)d_out;

    if (ws_size < (size_t)WS_FLOATS * sizeof(float)) {
        manifold_fused<<<BS_, 256, 0, stream>>>(
            x, Wf1, bf1v, Wf2, bf2v, Wg1, bg1v, Wg2, bg2v,
            Wk1, bk1v, Wk2, bk2v, out);
        return;
    }

    float* ws    = (float*)d_ws;
    float* sk    = ws + WS_SK;
    float* oacc  = ws + WS_OACC;
    float* opart = ws + WS_OPART;
    float* jpart = ws + WS_JPART;

    k12_l1l2  <<<384, 256, 0, stream>>>(x, Wf1, bf1v, Wg1, bg1v, Wk1, bk1v,
                                        Wf2, bf2v, Wg2, bg2v, Wk2, bk2v,
                                        sk, opart);
    k25_reduce<<<384, 256, 0, stream>>>(opart, oacc);
    k3_vj     <<<256, 256, 0, stream>>>(Wk1, Wk2, oacc, sk, jpart);
    k4_final  <<<BS_, 256, 0, stream>>>(oacc, jpart, out);
}

// Round 14
// 130.610 us; speedup vs baseline: 1.0873x; 1.0442x over previous
//
#include <hip/hip_runtime.h>
#include <stdint.h>

#define N_ 256
#define H_ 1024
#define BS_ 128

// ---------------- workspace layout (floats), all plain stores ----------------
// sk   : [128][1024]        @ 0          1 - tk^2
// oacc : [3][128][256]      @ 131072     reduced fo/go/ko
// opart: [16][3][128][256]  @ 229376     layer2 k-split partials
// jpart: [16][2][128][256]  @ 1802240    J h-split partials
#define WS_SK    0
#define WS_OACC  131072
#define WS_OPART 229376
#define WS_JPART 1802240
#define WS_FLOATS 2850816   // ~11.4 MB

// ---- K12: fused layer1+layer2-partial. grid = 48 groups x 8 row-tiles = 384 ----
// R11-optimal: 64-wide slices (full coalescing), 16 rows/block = 48 MB traffic.
// XCD swizzle: bx = g + 48*rt -> bx%8 == g%8.
__global__ __launch_bounds__(256) void k12_l1l2(
    const float* __restrict__ x,
    const float* __restrict__ Wf1, const float* __restrict__ bf1,
    const float* __restrict__ Wg1, const float* __restrict__ bg1,
    const float* __restrict__ Wk1, const float* __restrict__ bk1,
    const float* __restrict__ Wf2, const float* __restrict__ bf2,
    const float* __restrict__ Wg2, const float* __restrict__ bg2,
    const float* __restrict__ Wk2, const float* __restrict__ bk2,
    float* __restrict__ sk, float* __restrict__ opart)
{
    const int bx = blockIdx.x;
    const int g  = bx % 48;            // weight-sharing group
    const int rt = bx / 48;            // 0..7 row tile (16 rows)
    const int m  = g >> 4;             // 0..2
    const int ht = g & 15;             // 0..15  (64-wide h-slice = k-slice)
    const int t  = threadIdx.x;
    const int h0 = ht * 64;
    const int r0 = rt * 16;

    const float* W1 = (m == 0) ? Wf1 : (m == 1) ? Wg1 : Wk1;
    const float* b1 = (m == 0) ? bf1 : (m == 1) ? bg1 : bk1;
    const float* W2 = (m == 0) ? Wf2 : (m == 1) ? Wg2 : Wk2;
    const float* b2 = (m == 0) ? bf2 : (m == 1) ? bg2 : bk2;

    __shared__ float xs[16][256];      // 16 KB
    __shared__ float ts[16][64];       // 4 KB
    for (int u = t; u < 4096; u += 256)
        xs[u >> 8][u & 255] = x[(r0 + (u >> 8)) * N_ + (u & 255)];
    __syncthreads();

    // ---- phase 1: thread = (hl = t&63, row-quad rq = (t>>6)*4) ----
    {
        const int hl = t & 63;
        const int rq = (t >> 6) * 4;
        const int h  = h0 + hl;
        float a0 = b1[h], a1 = a0, a2 = a0, a3 = a0;
        const float4* w4 = (const float4*)(W1 + h * N_);
        const float4* x0 = (const float4*)xs[rq];
        const float4* x1 = (const float4*)xs[rq + 1];
        const float4* x2 = (const float4*)xs[rq + 2];
        const float4* x3 = (const float4*)xs[rq + 3];
        #pragma unroll 8
        for (int c = 0; c < 64; ++c) {
            float4 w = w4[c];
            float4 p = x0[c];                    // broadcast LDS reads
            a0 += w.x * p.x + w.y * p.y + w.z * p.z + w.w * p.w;
            float4 q = x1[c];
            a1 += w.x * q.x + w.y * q.y + w.z * q.z + w.w * q.w;
            float4 r = x2[c];
            a2 += w.x * r.x + w.y * r.y + w.z * r.z + w.w * r.w;
            float4 s = x3[c];
            a3 += w.x * s.x + w.y * s.y + w.z * s.z + w.w * s.w;
        }
        const float v0 = tanhf(a0), v1 = tanhf(a1);
        const float v2 = tanhf(a2), v3 = tanhf(a3);
        ts[rq][hl] = v0; ts[rq + 1][hl] = v1;
        ts[rq + 2][hl] = v2; ts[rq + 3][hl] = v3;
        if (m == 2) {
            sk[(r0 + rq) * H_ + h]     = 1.0f - v0 * v0;
            sk[(r0 + rq + 1) * H_ + h] = 1.0f - v1 * v1;
            sk[(r0 + rq + 2) * H_ + h] = 1.0f - v2 * v2;
            sk[(r0 + rq + 3) * H_ + h] = 1.0f - v3 * v3;
        }
    }
    __syncthreads();

    // ---- phase 2: thread = output channel i; 16-row partial over the slice --
    {
        float acc[16];
        const float bv = (ht == 0) ? b2[t] : 0.0f;
        #pragma unroll
        for (int r = 0; r < 16; ++r) acc[r] = bv;

        const float4* w4 = (const float4*)(W2 + t * H_ + h0);
        #pragma unroll 2
        for (int c = 0; c < 16; ++c) {
            float4 w = w4[c];
            #pragma unroll
            for (int r = 0; r < 16; ++r) {
                float4 a = ((const float4*)ts[r])[c];   // wave-uniform broadcast
                acc[r] += w.x * a.x + w.y * a.y + w.z * a.z + w.w * a.w;
            }
        }
        #pragma unroll
        for (int r = 0; r < 16; ++r)
            opart[((ht * 3 + m) * BS_ + r0 + r) * N_ + t] = acc[r];
    }
}

// ---- K25: reduce opart -> oacc once. grid = 384 blocks ----
__global__ __launch_bounds__(256) void k25_reduce(
    const float* __restrict__ opart, float* __restrict__ oacc)
{
    const int tid = blockIdx.x * 256 + threadIdx.x;   // 0..98303
    float s = 0.f;
    #pragma unroll
    for (int ks = 0; ks < 16; ++ks)
        s += opart[ks * (3 * BS_ * N_) + tid];
    oacc[tid] = s;
}

// ---- K3: fused v+J partials. grid = 32rp(4rows) x 16q(64h) = 512 ----
// R11-optimal: 2 blocks/CU, 64 MB traffic beats both traffic-halving variants.
// XCD swizzle: bx = q + 16*rp.
__global__ __launch_bounds__(256) void k3_vj(
    const float* __restrict__ Wk1, const float* __restrict__ Wk2,
    const float* __restrict__ oacc, const float* __restrict__ sk,
    float* __restrict__ jpart)
{
    const int q  = blockIdx.x & 15;    // 0..15 h-slice
    const int rp = blockIdx.x >> 4;    // 0..31 row tile
    const int t  = threadIdx.x;
    const int r0 = rp * 4;
    const int h0 = q * 64;

    __shared__ float fos[4][256], gos[4][256];   // 8 KB
    __shared__ float sfv[4][64], sgv[4][64];     // 2 KB

    // stage reduced fo/go rows (coalesced, 4 KB total reads)
    for (int u = t; u < 1024; u += 256) {
        const int r = u >> 8, i = u & 255;
        fos[r][i] = oacc[(r0 + r) * N_ + i];
        gos[r][i] = oacc[(BS_ + r0 + r) * N_ + i];
    }
    __syncthreads();

    // ---- phase A: v[r][h] = sum_i o[r][i]*Wk2[i][h]; thread = (h, r=wave) ----
    {
        const int hl = t & 63;
        const int rl = t >> 6;         // 0..3, wave-uniform
        const int h  = h0 + hl;
        const float* w2 = Wk2 + h;
        float vf = 0.f, vg = 0.f;
        #pragma unroll 8
        for (int c = 0; c < 64; ++c) {
            const float4 of = ((const float4*)fos[rl])[c];   // broadcast b128
            const float4 og = ((const float4*)gos[rl])[c];
            const float w0 = w2[(4 * c + 0) * H_];
            const float w1 = w2[(4 * c + 1) * H_];
            const float w2v = w2[(4 * c + 2) * H_];
            const float w3 = w2[(4 * c + 3) * H_];
            vf += of.x * w0 + of.y * w1 + of.z * w2v + of.w * w3;
            vg += og.x * w0 + og.y * w1 + og.z * w2v + og.w * w3;
        }
        const float s = sk[(r0 + rl) * H_ + h];
        sfv[rl][hl] = s * vf;
        sgv[rl][hl] = s * vg;
    }
    __syncthreads();

    // ---- phase B: J[r][j] = sum_hh sfv[r][hh]*Wk1[h0+hh][j]; thread = j ----
    {
        float jf[4] = {0.f, 0.f, 0.f, 0.f};
        float jg[4] = {0.f, 0.f, 0.f, 0.f};
        const float* w1 = Wk1 + h0 * N_ + t;    // coalesced over t
        #pragma unroll 4
        for (int c = 0; c < 16; ++c) {
            const float w0 = w1[(4 * c + 0) * N_];
            const float wv1 = w1[(4 * c + 1) * N_];
            const float wv2 = w1[(4 * c + 2) * N_];
            const float wv3 = w1[(4 * c + 3) * N_];
            #pragma unroll
            for (int r = 0; r < 4; ++r) {
                const float4 sf = ((const float4*)sfv[r])[c];   // ds_read_b128
                const float4 sg = ((const float4*)sgv[r])[c];
                jf[r] += sf.x * w0 + sf.y * wv1 + sf.z * wv2 + sf.w * wv3;
                jg[r] += sg.x * w0 + sg.y * wv1 + sg.z * wv2 + sg.w * wv3;
            }
        }
        #pragma unroll
        for (int r = 0; r < 4; ++r) {
            jpart[((q * 2 + 0) * BS_ + r0 + r) * N_ + t] = jf[r];
            jpart[((q * 2 + 1) * BS_ + r0 + r) * N_ + t] = jg[r];
        }
    }
}

// ---- K4: reduce jpart + norms + mask + output. grid = 128 ----
__global__ __launch_bounds__(256) void k4_final(
    const float* __restrict__ oacc,
    const float* __restrict__ jpart,
    float* __restrict__ out)
{
    const int r = blockIdx.x;
    const int t = threadIdx.x;
    __shared__ float red[12];

    const float fo = oacc[r * N_ + t];
    const float go = oacc[(BS_ + r) * N_ + t];
    const float ko = oacc[(2 * BS_ + r) * N_ + t];

    float jf = 0.f, jg = 0.f;
    #pragma unroll
    for (int q = 0; q < 16; ++q) {
        jf += jpart[((q * 2 + 0) * BS_ + r) * N_ + t];
        jg += jpart[((q * 2 + 1) * BS_ + r) * N_ + t];
    }

    float v0 = ko * ko, v1 = jf * jf, v2 = ko * jg;
    #pragma unroll
    for (int o = 32; o > 0; o >>= 1) {
        v0 += __shfl_xor(v0, o, 64);
        v1 += __shfl_xor(v1, o, 64);
        v2 += __shfl_xor(v2, o, 64);
    }
    const int wid = t >> 6;
    if ((t & 63) == 0) {
        red[wid * 3 + 0] = v0;
        red[wid * 3 + 1] = v1;
        red[wid * 3 + 2] = v2;
    }
    __syncthreads();
    const float kn2 = red[0] + red[3] + red[6] + red[9];
    const float jf2 = red[1] + red[4] + red[7] + red[10];
    const float kjg = red[2] + red[5] + red[8] + red[11];

    const float knorm = sqrtf(kn2);
    const float kn4 = kn2 * kn2;
    const float kn8 = kn4 * kn4;
    const float c1 = sqrtf(jf2) - 60.0f * kn8 * knorm;
    const float c2 = kjg - 20.0f * kn8 * kn2;
    const float scale = ((c1 > 1e-8f) || (c2 < -1e-8f)) ? 0.5f : 1.0f;

    out[r * N_ + t] = (fo + go) * scale;
}

// ================= fallback: round-2 proven fused kernel =================
__global__ __launch_bounds__(256) void manifold_fused(
    const float* __restrict__ x,
    const float* __restrict__ Wf1, const float* __restrict__ bf1v,
    const float* __restrict__ Wf2, const float* __restrict__ bf2v,
    const float* __restrict__ Wg1, const float* __restrict__ bg1v,
    const float* __restrict__ Wg2, const float* __restrict__ bg2v,
    const float* __restrict__ Wk1, const float* __restrict__ bk1v,
    const float* __restrict__ Wk2, const float* __restrict__ bk2v,
    float* __restrict__ out)
{
    const int b = blockIdx.x;
    const int t = threadIdx.x;
    __shared__ float xs[N_];
    __shared__ float tf[H_], tg[H_], tk[H_], sk[H_];
    __shared__ float fo[N_], go[N_];
    __shared__ float sfv[H_], sgv[H_];
    __shared__ float red[12];

    xs[t] = x[b * N_ + t];
    __syncthreads();
    {
        float acc[12];
        const float4* rows[12];
        #pragma unroll
        for (int m = 0; m < 4; ++m) {
            const int h = t + m * 256;
            rows[m]     = (const float4*)(Wf1 + h * N_);
            rows[4 + m] = (const float4*)(Wg1 + h * N_);
            rows[8 + m] = (const float4*)(Wk1 + h * N_);
            acc[m] = bf1v[h]; acc[4 + m] = bg1v[h]; acc[8 + m] = bk1v[h];
        }
        const float4* xs4 = (const float4*)xs;
        #pragma unroll 2
        for (int c = 0; c < 64; ++c) {
            float4 a = xs4[c];
            #pragma unroll
            for (int r = 0; r < 12; ++r) {
                float4 w = rows[r][c];
                acc[r] += w.x * a.x + w.y * a.y + w.z * a.z + w.w * a.w;
            }
        }
        #pragma unroll
        for (int m = 0; m < 4; ++m) {
            const int h = t + m * 256;
            float vtf = tanhf(acc[m]);
            float vtg = tanhf(acc[4 + m]);
            float vtk = tanhf(acc[8 + m]);
            tf[h] = vtf; tg[h] = vtg; tk[h] = vtk; sk[h] = 1.0f - vtk * vtk;
        }
    }
    __syncthreads();
    float af = bf2v[t], ag = bg2v[t], ak = bk2v[t];
    {
        const float4* rf = (const float4*)(Wf2 + t * H_);
        const float4* rg = (const float4*)(Wg2 + t * H_);
        const float4* rk = (const float4*)(Wk2 + t * H_);
        #pragma unroll 2
        for (int c = 0; c < 256; ++c) {
            float4 wf = rf[c], wg = rg[c], wk = rk[c];
            float4 vf = ((const float4*)tf)[c];
            af += wf.x*vf.x + wf.y*vf.y + wf.z*vf.z + wf.w*vf.w;
            float4 vg = ((const float4*)tg)[c];
            ag += wg.x*vg.x + wg.y*vg.y + wg.z*vg.z + wg.w*vg.w;
            float4 vk = ((const float4*)tk)[c];
            ak += wk.x*vk.x + wk.y*vk.y + wk.z*vk.z + wk.w*vk.w;
        }
    }
    fo[t] = af; go[t] = ag;
    __syncthreads();
    {
        float vf[4] = {0.f,0.f,0.f,0.f}, vg[4] = {0.f,0.f,0.f,0.f};
        const float* base = Wk2 + 4 * t;
        #pragma unroll 4
        for (int i = 0; i < N_; ++i) {
            float4 w = *(const float4*)(base + i * H_);
            float fv = fo[i], gv = go[i];
            vf[0]+=w.x*fv; vf[1]+=w.y*fv; vf[2]+=w.z*fv; vf[3]+=w.w*fv;
            vg[0]+=w.x*gv; vg[1]+=w.y*gv; vg[2]+=w.z*gv; vg[3]+=w.w*gv;
        }
        #pragma unroll
        for (int c = 0; c < 4; ++c) {
            sfv[4*t+c] = sk[4*t+c]*vf[c];
            sgv[4*t+c] = sk[4*t+c]*vg[c];
        }
    }
    __syncthreads();
    float jf = 0.f, jg = 0.f;
    {
        const float* col = Wk1 + t;
        #pragma unroll 4
        for (int c = 0; c < 256; ++c) {
            float4 s4 = ((const float4*)sfv)[c];
            float4 g4 = ((const float4*)sgv)[c];
            const int h = c * 4;
            float w0 = col[(h+0)*N_], w1 = col[(h+1)*N_];
            float w2 = col[(h+2)*N_], w3 = col[(h+3)*N_];
            jf += s4.x*w0 + s4.y*w1 + s4.z*w2 + s4.w*w3;
            jg += g4.x*w0 + g4.y*w1 + g4.z*w2 + g4.w*w3;
        }
    }
    float v0 = ak*ak, v1 = jf*jf, v2 = ak*jg;
    #pragma unroll
    for (int o = 32; o > 0; o >>= 1) {
        v0 += __shfl_xor(v0, o, 64);
        v1 += __shfl_xor(v1, o, 64);
        v2 += __shfl_xor(v2, o, 64);
    }
    const int wid = t >> 6;
    if ((t & 63) == 0) {
        red[wid*3+0] = v0; red[wid*3+1] = v1; red[wid*3+2] = v2;
    }
    __syncthreads();
    const float kn2 = red[0]+red[3]+red[6]+red[9];
    const float jf2 = red[1]+red[4]+red[7]+red[10];
    const float kjg = red[2]+red[5]+red[8]+red[11];
    const float knorm = sqrtf(kn2);
    const float kn4 = kn2*kn2, kn8 = kn4*kn4;
    const float c1 = sqrtf(jf2) - 60.0f*kn8*knorm;
    const float c2 = kjg - 20.0f*kn8*kn2;
    const float scale = ((c1 > 1e-8f) || (c2 < -1e-8f)) ? 0.5f : 1.0f;
    out[b*N_+t] = (af+ag)*scale;
}

extern "C" void kernel_launch(void* const* d_in, const int* in_sizes, int n_in,
                              void* d_out, int out_size, void* d_ws, size_t ws_size,
                              hipStream_t stream) {
    const float* x    = (const float*)d_in[1];
    const float* Wf1  = (const float*)d_in[2];
    const float* bf1v = (const float*)d_in[3];
    const float* Wf2  = (const float*)d_in[4];
    const float* bf2v = (const float*)d_in[5];
    const float* Wg1  = (const float*)d_in[6];
    const float* bg1v = (const float*)d_in[7];
    const float* Wg2  = (const float*)d_in[8];
    const float* bg2v = (const float*)d_in[9];
    const float* Wk1  = (const float*)d_in[10];
    const float* bk1v = (const float*)d_in[11];
    const float* Wk2  = (const float*)d_in[12];
    const float* bk2v = (const float*)d_in[13];
    float* out = (float*)d_out;

    if (ws_size < (size_t)WS_FLOATS * sizeof(float)) {
        manifold_fused<<<BS_, 256, 0, stream>>>(
            x, Wf1, bf1v, Wf2, bf2v, Wg1, bg1v, Wg2, bg2v,
            Wk1, bk1v, Wk2, bk2v, out);
        return;
    }

    float* ws    = (float*)d_ws;
    float* sk    = ws + WS_SK;
    float* oacc  = ws + WS_OACC;
    float* opart = ws + WS_OPART;
    float* jpart = ws + WS_JPART;

    k12_l1l2  <<<384, 256, 0, stream>>>(x, Wf1, bf1v, Wg1, bg1v, Wk1, bk1v,
                                        Wf2, bf2v, Wg2, bg2v, Wk2, bk2v,
                                        sk, opart);
    k25_reduce<<<384, 256, 0, stream>>>(opart, oacc);
    k3_vj     <<<512, 256, 0, stream>>>(Wk1, Wk2, oacc, sk, jpart);
    k4_final  <<<BS_, 256, 0, stream>>>(oacc, jpart, out);
}